// Round 1
// baseline (9005.955 us; speedup 1.0000x reference)
//
#include <hip/hip_runtime.h>
#include <hip/hip_bf16.h>
#include <math.h>

// Problem constants
#define Tn 2048
#define Dn 3584
#define NH 28
#define KHn 4
#define Hn 128
#define Gn 7            // NH / KHn

// ---------------------------------------------------------------------------
// Generic fp32 GEMM with optional bias: C[M x Nc] = A[M x K] * B[K x Nc] + bias
// Block tile 64x64, 256 threads, 4x4 per-thread micro-tile, K-tile 16.
// Assumes M%64==0, Nc%64==0, K%16==0 (true for all our shapes).
// ---------------------------------------------------------------------------
#define TM 64
#define TN 64
#define TK 16

__global__ __launch_bounds__(256) void gemm_bias_f32(
    const float* __restrict__ A, const float* __restrict__ B,
    const float* __restrict__ bias, float* __restrict__ C,
    int M, int Nc, int K)
{
    __shared__ __align__(16) float As[TK][TM + 4];
    __shared__ __align__(16) float Bs[TK][TN + 4];

    const int tid = threadIdx.x;
    const int bm = blockIdx.y * TM;
    const int bn = blockIdx.x * TN;
    const int tx = tid & 15;        // n-group
    const int ty = tid >> 4;        // m-group

    const int arow = tid >> 2;            // 0..63
    const int acol = (tid & 3) * 4;       // 0,4,8,12
    const int brow = tid >> 4;            // 0..15
    const int bcol = (tid & 15) * 4;      // 0..60

    float acc[4][4] = {};

    for (int k0 = 0; k0 < K; k0 += TK) {
        // Stage A tile (64 x 16), stored transposed As[k][m]
        const float4 a4 = *(const float4*)(A + (size_t)(bm + arow) * K + k0 + acol);
        As[acol + 0][arow] = a4.x;
        As[acol + 1][arow] = a4.y;
        As[acol + 2][arow] = a4.z;
        As[acol + 3][arow] = a4.w;
        // Stage B tile (16 x 64), Bs[k][n]; (TN+4)=68 floats -> 272B row stride,
        // 16B-aligned at bcol multiples of 4 floats => float4 store is legal.
        const float4 b4 = *(const float4*)(B + (size_t)(k0 + brow) * Nc + bn + bcol);
        *(float4*)&Bs[brow][bcol] = b4;
        __syncthreads();

        #pragma unroll
        for (int kk = 0; kk < TK; ++kk) {
            const float4 av = *(const float4*)&As[kk][ty * 4];
            const float4 bv = *(const float4*)&Bs[kk][tx * 4];
            const float a[4] = {av.x, av.y, av.z, av.w};
            const float b[4] = {bv.x, bv.y, bv.z, bv.w};
            #pragma unroll
            for (int i = 0; i < 4; ++i)
                #pragma unroll
                for (int j = 0; j < 4; ++j)
                    acc[i][j] += a[i] * b[j];
        }
        __syncthreads();
    }

    #pragma unroll
    for (int i = 0; i < 4; ++i) {
        const int row = bm + ty * 4 + i;
        #pragma unroll
        for (int j = 0; j < 4; ++j) {
            const int col = bn + tx * 4 + j;
            float vout = acc[i][j];
            if (bias) vout += bias[col];
            C[(size_t)row * Nc + col] = vout;
        }
    }
}

// ---------------------------------------------------------------------------
// RoPE in place on x: (T, heads, 128). sin/cos: (T, 64).
// ---------------------------------------------------------------------------
__global__ void rope_f32(float* __restrict__ x,
                         const float* __restrict__ sin_t,
                         const float* __restrict__ cos_t,
                         int heads)
{
    const int total = Tn * 64 * 1;      // per-head pairs handled via heads dim
    const int idx = blockIdx.x * blockDim.x + threadIdx.x;
    const int n_elem = Tn * heads * 64;
    if (idx >= n_elem) return;
    const int i = idx & 63;
    const int nh = (idx >> 6) % heads;
    const int t = idx / (64 * heads);
    const float s = sin_t[t * 64 + i];
    const float c = cos_t[t * 64 + i];
    float* p = x + ((size_t)t * heads + nh) * Hn;
    const float x1 = p[i];
    const float x2 = p[i + 64];
    p[i]      = x1 * c - x2 * s;
    p[i + 64] = x2 * c + x1 * s;
    (void)total;
}

// ---------------------------------------------------------------------------
// Attention: one block (256 thr) per (query t, head n). Causal.
// q: (T, NH, 128), k/v: (T, KHn, 128), o: (T, NH, 128)
// ---------------------------------------------------------------------------
__global__ __launch_bounds__(256) void attn_f32(
    const float* __restrict__ q, const float* __restrict__ k,
    const float* __restrict__ v, float* __restrict__ o)
{
    const int t = blockIdx.x;
    const int n = blockIdx.y;
    const int kh = n / Gn;
    const int tid = threadIdx.x;

    __shared__ __align__(16) float qs[Hn];
    __shared__ __align__(16) float sc[Tn];
    __shared__ __align__(16) float red[256];

    if (tid < Hn) qs[tid] = q[((size_t)t * NH + n) * Hn + tid];
    __syncthreads();

    const float scale = 0.08838834764831845f;   // 1/sqrt(128)

    // scores
    float lmax = -3.4e38f;
    for (int s = tid; s <= t; s += 256) {
        const float4* kr = (const float4*)(k + ((size_t)s * KHn + kh) * Hn);
        const float4* qr = (const float4*)qs;
        float d = 0.f;
        #pragma unroll
        for (int c4 = 0; c4 < Hn / 4; ++c4) {
            const float4 kk4 = kr[c4];
            const float4 qq4 = qr[c4];
            d += qq4.x * kk4.x + qq4.y * kk4.y + qq4.z * kk4.z + qq4.w * kk4.w;
        }
        d *= scale;
        sc[s] = d;
        lmax = fmaxf(lmax, d);
    }

    // block max
    red[tid] = lmax;
    __syncthreads();
    #pragma unroll
    for (int w = 128; w > 0; w >>= 1) {
        if (tid < w) red[tid] = fmaxf(red[tid], red[tid + w]);
        __syncthreads();
    }
    const float m = red[0];
    __syncthreads();

    // exp + sum
    float lsum = 0.f;
    for (int s = tid; s <= t; s += 256) {
        const float e = __expf(sc[s] - m);
        sc[s] = e;
        lsum += e;
    }
    red[tid] = lsum;
    __syncthreads();
    #pragma unroll
    for (int w = 128; w > 0; w >>= 1) {
        if (tid < w) red[tid] += red[tid + w];
        __syncthreads();
    }
    const float ssum = red[0];
    __syncthreads();

    // PV: two s-halves, 128 columns
    const int c = tid & 127;
    const int half = tid >> 7;
    float acc = 0.f;
    for (int s = half; s <= t; s += 2)
        acc += sc[s] * v[((size_t)s * KHn + kh) * Hn + c];
    red[tid] = acc;
    __syncthreads();
    if (tid < 128) {
        const float res = (red[tid] + red[tid + 128]) / ssum;
        o[((size_t)t * NH + n) * Hn + tid] = res;
    }
}

// ---------------------------------------------------------------------------
// Launch
// ---------------------------------------------------------------------------
extern "C" void kernel_launch(void* const* d_in, const int* in_sizes, int n_in,
                              void* d_out, int out_size, void* d_ws, size_t ws_size,
                              hipStream_t stream)
{
    const float* x      = (const float*)d_in[0];
    // d_in[1] = attn_mask (causal tril) -- applied analytically, not read
    const float* sin_t  = (const float*)d_in[2];
    const float* cos_t  = (const float*)d_in[3];
    const float* wq     = (const float*)d_in[4];
    const float* wk     = (const float*)d_in[5];
    const float* wv     = (const float*)d_in[6];
    const float* wo     = (const float*)d_in[7];
    const float* q_bias = (const float*)d_in[8];
    const float* k_bias = (const float*)d_in[9];
    const float* v_bias = (const float*)d_in[10];
    float* out = (float*)d_out;

    // Workspace layout (fp32)
    float* qbuf  = (float*)d_ws;                        // T x 3584
    float* kbuf  = qbuf + (size_t)Tn * Dn;              // T x 512
    float* vbuf  = kbuf + (size_t)Tn * (KHn * Hn);      // T x 512
    float* abuf  = vbuf + (size_t)Tn * (KHn * Hn);      // T x 3584

    // QKV projections
    gemm_bias_f32<<<dim3(Dn / TN, Tn / TM), 256, 0, stream>>>(
        x, wq, q_bias, qbuf, Tn, Dn, Dn);
    gemm_bias_f32<<<dim3((KHn * Hn) / TN, Tn / TM), 256, 0, stream>>>(
        x, wk, k_bias, kbuf, Tn, KHn * Hn, Dn);
    gemm_bias_f32<<<dim3((KHn * Hn) / TN, Tn / TM), 256, 0, stream>>>(
        x, wv, v_bias, vbuf, Tn, KHn * Hn, Dn);

    // RoPE on q and k
    {
        const int nq = Tn * NH * 64;
        rope_f32<<<(nq + 255) / 256, 256, 0, stream>>>(qbuf, sin_t, cos_t, NH);
        const int nk = Tn * KHn * 64;
        rope_f32<<<(nk + 255) / 256, 256, 0, stream>>>(kbuf, sin_t, cos_t, KHn);
    }

    // Attention
    attn_f32<<<dim3(Tn, NH), 256, 0, stream>>>(qbuf, kbuf, vbuf, abuf);

    // Output projection (no bias)
    gemm_bias_f32<<<dim3(Dn / TN, Tn / TM), 256, 0, stream>>>(
        abuf, wo, nullptr, out, Tn, Dn, Dn);
}

// Round 2
// 2953.782 us; speedup vs baseline: 3.0490x; 3.0490x over previous
//
#include <hip/hip_runtime.h>
#include <hip/hip_bf16.h>
#include <math.h>

// Problem constants
#define Tn 2048
#define Dn 3584
#define NH 28
#define KHn 4
#define Hn 128
#define Gn 7            // NH / KHn
#define BQ 64
#define BS 64
#define SCALE 0.08838834764831845f  // 1/sqrt(128)

// ---------------------------------------------------------------------------
// Generic fp32 GEMM with optional bias: C[M x Nc] = A[M x K] * B[K x Nc] + bias
// Block tile 64x64, 256 threads, 4x4 per-thread micro-tile, K-tile 16.
// ---------------------------------------------------------------------------
#define TM 64
#define TN 64
#define TK 16

__global__ __launch_bounds__(256) void gemm_bias_f32(
    const float* __restrict__ A, const float* __restrict__ B,
    const float* __restrict__ bias, float* __restrict__ C,
    int M, int Nc, int K)
{
    __shared__ __align__(16) float As[TK][TM + 4];
    __shared__ __align__(16) float Bs[TK][TN + 4];

    const int tid = threadIdx.x;
    const int bm = blockIdx.y * TM;
    const int bn = blockIdx.x * TN;
    const int tx = tid & 15;
    const int ty = tid >> 4;

    const int arow = tid >> 2;
    const int acol = (tid & 3) * 4;
    const int brow = tid >> 4;
    const int bcol = (tid & 15) * 4;

    float acc[4][4] = {};

    for (int k0 = 0; k0 < K; k0 += TK) {
        const float4 a4 = *(const float4*)(A + (size_t)(bm + arow) * K + k0 + acol);
        As[acol + 0][arow] = a4.x;
        As[acol + 1][arow] = a4.y;
        As[acol + 2][arow] = a4.z;
        As[acol + 3][arow] = a4.w;
        const float4 b4 = *(const float4*)(B + (size_t)(k0 + brow) * Nc + bn + bcol);
        *(float4*)&Bs[brow][bcol] = b4;
        __syncthreads();

        #pragma unroll
        for (int kk = 0; kk < TK; ++kk) {
            const float4 av = *(const float4*)&As[kk][ty * 4];
            const float4 bv = *(const float4*)&Bs[kk][tx * 4];
            const float a[4] = {av.x, av.y, av.z, av.w};
            const float b[4] = {bv.x, bv.y, bv.z, bv.w};
            #pragma unroll
            for (int i = 0; i < 4; ++i)
                #pragma unroll
                for (int j = 0; j < 4; ++j)
                    acc[i][j] += a[i] * b[j];
        }
        __syncthreads();
    }

    #pragma unroll
    for (int i = 0; i < 4; ++i) {
        const int row = bm + ty * 4 + i;
        #pragma unroll
        for (int j = 0; j < 4; ++j) {
            const int col = bn + tx * 4 + j;
            float vout = acc[i][j];
            if (bias) vout += bias[col];
            C[(size_t)row * Nc + col] = vout;
        }
    }
}

// ---------------------------------------------------------------------------
// RoPE in place on x: (T, heads, 128). sin/cos: (T, 64).
// ---------------------------------------------------------------------------
__global__ void rope_f32(float* __restrict__ x,
                         const float* __restrict__ sin_t,
                         const float* __restrict__ cos_t,
                         int heads)
{
    const int idx = blockIdx.x * blockDim.x + threadIdx.x;
    const int n_elem = Tn * heads * 64;
    if (idx >= n_elem) return;
    const int i = idx & 63;
    const int nh = (idx >> 6) % heads;
    const int t = idx / (64 * heads);
    const float s = sin_t[t * 64 + i];
    const float c = cos_t[t * 64 + i];
    float* p = x + ((size_t)t * heads + nh) * Hn;
    const float x1 = p[i];
    const float x2 = p[i + 64];
    p[i]      = x1 * c - x2 * s;
    p[i + 64] = x2 * c + x1 * s;
}

// ---------------------------------------------------------------------------
// Flash-style fp32 attention.
// Block = (q-tile of 64 rows, head n). 256 threads (16x16).
// QK^T: 64x64x128 register-tile GEMM (4x4/thread), K staged in 32-d chunks.
// Online softmax in LDS; PV: 64x128x64 GEMM, V staged in 16-s chunks.
// q,o: (T, NH, 128); k,v: (T, KHn, 128).
// ---------------------------------------------------------------------------
__global__ __launch_bounds__(256) void flash_attn_f32(
    const float* __restrict__ q, const float* __restrict__ k,
    const float* __restrict__ v, float* __restrict__ o)
{
    const int qt = (int)(gridDim.x - 1 - blockIdx.x);   // heavy tiles first
    const int n  = blockIdx.y;
    const int kh = n / Gn;
    const int tid = threadIdx.x;
    const int tx = tid & 15;
    const int ty = tid >> 4;

    __shared__ __align__(16) float Qs[Hn][BQ + 4];   // [d][m], scaled
    __shared__ __align__(16) float Ks[32][BS + 4];   // [d-chunk][s]
    __shared__ __align__(16) float Sc[BQ][BS + 4];   // scores / P
    __shared__ __align__(16) float Vs[16][Hn + 4];   // [s-chunk][d]
    __shared__ float mrow[BQ], lrow[BQ], arow[BQ];
    __shared__ float red[256];

    // ---- load Q tile (transposed into LDS, pre-scaled) ----
    {
        const int m  = tid >> 2;
        const int c0 = (tid & 3) * 32;
        const float* qrow = q + ((size_t)(qt * BQ + m) * NH + n) * Hn + c0;
        #pragma unroll
        for (int c4 = 0; c4 < 8; ++c4) {
            const float4 t4 = *(const float4*)(qrow + c4 * 4);
            Qs[c0 + c4 * 4 + 0][m] = t4.x * SCALE;
            Qs[c0 + c4 * 4 + 1][m] = t4.y * SCALE;
            Qs[c0 + c4 * 4 + 2][m] = t4.z * SCALE;
            Qs[c0 + c4 * 4 + 3][m] = t4.w * SCALE;
        }
    }
    if (tid < BQ) { mrow[tid] = -3.0e38f; lrow[tid] = 0.f; }

    float oacc[4][8] = {};   // rows ty*4+i ; cols {tx*4+u, 64+tx*4+u}

    for (int st = 0; st <= qt; ++st) {
        // ---------------- QK^T ----------------
        float sacc[4][4] = {};
        #pragma unroll 1
        for (int dc = 0; dc < 4; ++dc) {
            __syncthreads();   // Ks (and, on entry, Sc/Vs) free for reuse
            {
                const int s  = tid >> 2;
                const int c0 = (tid & 3) * 8;
                const float* krow = k + ((size_t)(st * BS + s) * KHn + kh) * Hn + dc * 32 + c0;
                const float4 k0 = *(const float4*)(krow);
                const float4 k1 = *(const float4*)(krow + 4);
                Ks[c0 + 0][s] = k0.x; Ks[c0 + 1][s] = k0.y;
                Ks[c0 + 2][s] = k0.z; Ks[c0 + 3][s] = k0.w;
                Ks[c0 + 4][s] = k1.x; Ks[c0 + 5][s] = k1.y;
                Ks[c0 + 6][s] = k1.z; Ks[c0 + 7][s] = k1.w;
            }
            __syncthreads();
            #pragma unroll
            for (int kk = 0; kk < 32; ++kk) {
                const float4 av = *(const float4*)&Qs[dc * 32 + kk][ty * 4];
                const float4 bv = *(const float4*)&Ks[kk][tx * 4];
                const float a[4] = {av.x, av.y, av.z, av.w};
                const float b[4] = {bv.x, bv.y, bv.z, bv.w};
                #pragma unroll
                for (int i = 0; i < 4; ++i)
                    #pragma unroll
                    for (int j = 0; j < 4; ++j)
                        sacc[i][j] += a[i] * b[j];
            }
        }

        // causal mask (only the diagonal tile can clip)
        if (st == qt) {
            #pragma unroll
            for (int i = 0; i < 4; ++i)
                #pragma unroll
                for (int j = 0; j < 4; ++j)
                    if (tx * 4 + j > ty * 4 + i) sacc[i][j] = -3.0e38f;
        }

        // store scores
        #pragma unroll
        for (int i = 0; i < 4; ++i)
            *(float4*)&Sc[ty * 4 + i][tx * 4] =
                make_float4(sacc[i][0], sacc[i][1], sacc[i][2], sacc[i][3]);
        __syncthreads();

        // row stats: max, alpha
        if (tid < BQ) {
            float rmax = -3.0e38f;
            #pragma unroll
            for (int j4 = 0; j4 < 16; ++j4) {
                const float4 s4 = *(const float4*)&Sc[tid][j4 * 4];
                rmax = fmaxf(rmax, fmaxf(fmaxf(s4.x, s4.y), fmaxf(s4.z, s4.w)));
            }
            const float mnew = fmaxf(mrow[tid], rmax);
            arow[tid] = __expf(mrow[tid] - mnew);
            mrow[tid] = mnew;
        }
        __syncthreads();

        // rescale O accumulator
        #pragma unroll
        for (int i = 0; i < 4; ++i) {
            const float a = arow[ty * 4 + i];
            #pragma unroll
            for (int j = 0; j < 8; ++j) oacc[i][j] *= a;
        }

        // exp pass + partial row sums
        {
            const int r  = tid >> 2;
            const int c0 = (tid & 3) * 16;
            const float mr = mrow[r];
            float psum = 0.f;
            #pragma unroll
            for (int c4 = 0; c4 < 4; ++c4) {
                float4 s4 = *(float4*)&Sc[r][c0 + c4 * 4];
                s4.x = __expf(s4.x - mr);
                s4.y = __expf(s4.y - mr);
                s4.z = __expf(s4.z - mr);
                s4.w = __expf(s4.w - mr);
                *(float4*)&Sc[r][c0 + c4 * 4] = s4;
                psum += s4.x + s4.y + s4.z + s4.w;
            }
            red[tid] = psum;
        }
        __syncthreads();
        if (tid < BQ)
            lrow[tid] = lrow[tid] * arow[tid] +
                        red[tid * 4] + red[tid * 4 + 1] +
                        red[tid * 4 + 2] + red[tid * 4 + 3];

        // ---------------- PV ----------------
        #pragma unroll 1
        for (int sc4 = 0; sc4 < 4; ++sc4) {
            __syncthreads();   // Vs free
            {
                const int s  = tid >> 4;
                const int d0 = (tid & 15) * 8;
                const float* vrow = v + ((size_t)(st * BS + sc4 * 16 + s) * KHn + kh) * Hn + d0;
                *(float4*)&Vs[s][d0]     = *(const float4*)(vrow);
                *(float4*)&Vs[s][d0 + 4] = *(const float4*)(vrow + 4);
            }
            __syncthreads();
            #pragma unroll
            for (int ss = 0; ss < 16; ++ss) {
                const float4 v0 = *(const float4*)&Vs[ss][tx * 4];
                const float4 v1 = *(const float4*)&Vs[ss][64 + tx * 4];
                #pragma unroll
                for (int i = 0; i < 4; ++i) {
                    const float p = Sc[ty * 4 + i][sc4 * 16 + ss];
                    oacc[i][0] += p * v0.x; oacc[i][1] += p * v0.y;
                    oacc[i][2] += p * v0.z; oacc[i][3] += p * v0.w;
                    oacc[i][4] += p * v1.x; oacc[i][5] += p * v1.y;
                    oacc[i][6] += p * v1.z; oacc[i][7] += p * v1.w;
                }
            }
        }
    }
    __syncthreads();

    // epilogue: divide by l, store
    #pragma unroll
    for (int i = 0; i < 4; ++i) {
        const int m = ty * 4 + i;
        const float inv = 1.0f / lrow[m];
        float* orow = o + ((size_t)(qt * BQ + m) * NH + n) * Hn;
        *(float4*)(orow + tx * 4) =
            make_float4(oacc[i][0] * inv, oacc[i][1] * inv, oacc[i][2] * inv, oacc[i][3] * inv);
        *(float4*)(orow + 64 + tx * 4) =
            make_float4(oacc[i][4] * inv, oacc[i][5] * inv, oacc[i][6] * inv, oacc[i][7] * inv);
    }
}

// ---------------------------------------------------------------------------
// Launch
// ---------------------------------------------------------------------------
extern "C" void kernel_launch(void* const* d_in, const int* in_sizes, int n_in,
                              void* d_out, int out_size, void* d_ws, size_t ws_size,
                              hipStream_t stream)
{
    const float* x      = (const float*)d_in[0];
    const float* sin_t  = (const float*)d_in[2];
    const float* cos_t  = (const float*)d_in[3];
    const float* wq     = (const float*)d_in[4];
    const float* wk     = (const float*)d_in[5];
    const float* wv     = (const float*)d_in[6];
    const float* wo     = (const float*)d_in[7];
    const float* q_bias = (const float*)d_in[8];
    const float* k_bias = (const float*)d_in[9];
    const float* v_bias = (const float*)d_in[10];
    float* out = (float*)d_out;

    float* qbuf = (float*)d_ws;                       // T x 3584
    float* kbuf = qbuf + (size_t)Tn * Dn;             // T x 512
    float* vbuf = kbuf + (size_t)Tn * (KHn * Hn);     // T x 512
    float* abuf = vbuf + (size_t)Tn * (KHn * Hn);     // T x 3584

    gemm_bias_f32<<<dim3(Dn / TN, Tn / TM), 256, 0, stream>>>(
        x, wq, q_bias, qbuf, Tn, Dn, Dn);
    gemm_bias_f32<<<dim3((KHn * Hn) / TN, Tn / TM), 256, 0, stream>>>(
        x, wk, k_bias, kbuf, Tn, KHn * Hn, Dn);
    gemm_bias_f32<<<dim3((KHn * Hn) / TN, Tn / TM), 256, 0, stream>>>(
        x, wv, v_bias, vbuf, Tn, KHn * Hn, Dn);

    {
        const int nq = Tn * NH * 64;
        rope_f32<<<(nq + 255) / 256, 256, 0, stream>>>(qbuf, sin_t, cos_t, NH);
        const int nk = Tn * KHn * 64;
        rope_f32<<<(nk + 255) / 256, 256, 0, stream>>>(kbuf, sin_t, cos_t, KHn);
    }

    flash_attn_f32<<<dim3(Tn / BQ, NH), 256, 0, stream>>>(qbuf, kbuf, vbuf, abuf);

    gemm_bias_f32<<<dim3(Dn / TN, Tn / TM), 256, 0, stream>>>(
        abuf, wo, nullptr, out, Tn, Dn, Dn);
}

// Round 3
// 1413.694 us; speedup vs baseline: 6.3705x; 2.0894x over previous
//
#include <hip/hip_runtime.h>
#include <hip/hip_bf16.h>
#include <math.h>

// Problem constants
#define Tn 2048
#define Dn 3584
#define NH 28
#define KHn 4
#define Hn 128
#define Gn 7            // NH / KHn
#define BQ 64
#define BS 64
#define SCALE 0.08838834764831845f  // 1/sqrt(128)
#define LDC 4608        // combined qkv row stride (q:0..3583, k:3584..4095, v:4096..4607)
#define KOFF 3584
#define VOFF 4096

typedef unsigned short u16;
typedef __attribute__((ext_vector_type(8))) short short8;   // 8 bf16 (4 VGPRs)
typedef __attribute__((ext_vector_type(4))) float floatx4;  // MFMA acc

// ---------------- bf16 helpers ----------------
__device__ __forceinline__ float bf_lo(unsigned int u) {
    union { unsigned int i; float f; } x; x.i = u << 16; return x.f;
}
__device__ __forceinline__ float bf_hi(unsigned int u) {
    union { unsigned int i; float f; } x; x.i = u & 0xffff0000u; return x.f;
}
__device__ __forceinline__ u16 f2bf(float f) {
    __hip_bfloat16 h = __float2bfloat16(f);
    return *reinterpret_cast<u16*>(&h);
}

// ---------------------------------------------------------------------------
// x fp32 -> bf16 cast (vectorized)
// ---------------------------------------------------------------------------
__global__ void cast_f32_bf16(const float* __restrict__ in, u16* __restrict__ out, int n4)
{
    const int idx = blockIdx.x * blockDim.x + threadIdx.x;
    if (idx >= n4) return;
    const float4 f = ((const float4*)in)[idx];
    ((ushort4*)out)[idx] = make_ushort4(f2bf(f.x), f2bf(f.y), f2bf(f.z), f2bf(f.w));
}

// ---------------------------------------------------------------------------
// Transpose + cast: out[c][r] = bf16(in[r][c]); in (R x C) fp32, out stride ldo.
// 32x32 LDS tiles, 256 threads.
// ---------------------------------------------------------------------------
__global__ __launch_bounds__(256) void transpose_cast(
    const float* __restrict__ in, u16* __restrict__ out, int R, int C, int ldo)
{
    __shared__ float ts[32][33];
    const int tid = threadIdx.x;
    const int c0 = blockIdx.x * 32, r0 = blockIdx.y * 32;
    const int tx = tid & 31, ty = tid >> 5;  // ty 0..7
    #pragma unroll
    for (int i = 0; i < 4; ++i)
        ts[ty + i * 8][tx] = in[(size_t)(r0 + ty + i * 8) * C + c0 + tx];
    __syncthreads();
    #pragma unroll
    for (int i = 0; i < 4; ++i)
        out[(size_t)(c0 + ty + i * 8) * ldo + r0 + tx] = f2bf(ts[tx][ty + i * 8]);
}

// ---------------------------------------------------------------------------
// Concat bias: [q_bias | k_bias | v_bias] -> 4608
// ---------------------------------------------------------------------------
__global__ void concat_bias(const float* __restrict__ qb, const float* __restrict__ kb,
                            const float* __restrict__ vb, float* __restrict__ out)
{
    const int j = blockIdx.x * blockDim.x + threadIdx.x;
    if (j >= 4608) return;
    out[j] = j < 3584 ? qb[j] : (j < 4096 ? kb[j - 3584] : vb[j - 4096]);
}

// ---------------------------------------------------------------------------
// bf16 MFMA GEMM (m97 structure): C[M x N] = A[M x K] * Bt[N x K]^T (+bias)
// 128x128 tile, BK=32, 256 thr (4 waves, 2x2 of 64x64), 16x16x32 MFMA.
// global_load_lds width-16 staging; LDS tiles row-major [row][k].
// OUT_T = u16 (bf16 store) or float.
// ---------------------------------------------------------------------------
#define GM 128
#define GN 128
#define GK 32

__device__ __forceinline__ void async16(const void* g, void* l) {
    __builtin_amdgcn_global_load_lds(
        (const __attribute__((address_space(1))) unsigned int*)g,
        (__attribute__((address_space(3))) unsigned int*)l, 16, 0, 0);
}

template <typename OUT_T>
__global__ __launch_bounds__(256) void gemm_bf16_mfma(
    const u16* __restrict__ A, const u16* __restrict__ Bt,
    const float* __restrict__ bias, OUT_T* __restrict__ C,
    int M, int N, int K, int ldc)
{
    __shared__ __align__(16) u16 As[GM * GK];   // 8 KB
    __shared__ __align__(16) u16 Bs[GN * GK];   // 8 KB

    const int tid  = threadIdx.x;
    const int lane = tid & 63;
    const int wave = tid >> 6;
    const int wr = wave >> 1, wc = wave & 1;
    const int m16 = lane & 15, quad = lane >> 4;

    const int bm = blockIdx.y * GM;
    const int bn = blockIdx.x * GN;

    floatx4 acc[4][4];
    #pragma unroll
    for (int i = 0; i < 4; ++i)
        #pragma unroll
        for (int j = 0; j < 4; ++j) acc[i][j] = (floatx4)0.f;

    const int rl   = lane >> 2;          // 0..15: row within 16-row chunk
    const int kcol = (lane & 3) * 8;     // k element offset of this lane's 16B

    for (int k0 = 0; k0 < K; k0 += GK) {
        __syncthreads();
        #pragma unroll
        for (int i = 0; i < 2; ++i) {
            const int c = wave + i * 4;          // chunk 0..7 (16 rows each)
            const int row = c * 16 + rl;
            async16(A  + (size_t)(bm + row) * K + k0 + kcol, &As[c * 512]);
            async16(Bt + (size_t)(bn + row) * K + k0 + kcol, &Bs[c * 512]);
        }
        __builtin_amdgcn_s_waitcnt(0);
        __syncthreads();

        short8 af[4], bfr[4];
        #pragma unroll
        for (int i = 0; i < 4; ++i)
            af[i] = *(const short8*)&As[(wr * 64 + i * 16 + m16) * GK + quad * 8];
        #pragma unroll
        for (int j = 0; j < 4; ++j)
            bfr[j] = *(const short8*)&Bs[(wc * 64 + j * 16 + m16) * GK + quad * 8];
        #pragma unroll
        for (int i = 0; i < 4; ++i)
            #pragma unroll
            for (int j = 0; j < 4; ++j)
                acc[i][j] = __builtin_amdgcn_mfma_f32_16x16x32_bf16(
                    af[i], bfr[j], acc[i][j], 0, 0, 0);
    }

    // epilogue: C/D layout col=lane&15, row=quad*4+reg
    #pragma unroll
    for (int j = 0; j < 4; ++j) {
        const int col = bn + wc * 64 + j * 16 + m16;
        const float bv = bias ? bias[col] : 0.f;
        #pragma unroll
        for (int i = 0; i < 4; ++i) {
            const int rbase = bm + wr * 64 + i * 16 + quad * 4;
            #pragma unroll
            for (int r = 0; r < 4; ++r) {
                const float v = acc[i][j][r] + bv;
                if constexpr (sizeof(OUT_T) == 2)
                    C[(size_t)(rbase + r) * ldc + col] = (OUT_T)f2bf(v);
                else
                    C[(size_t)(rbase + r) * ldc + col] = v;
            }
        }
    }
}

// ---------------------------------------------------------------------------
// RoPE in place on bf16 strided buffer: rows t (stride LDC), heads x 128.
// ---------------------------------------------------------------------------
__global__ void rope_bf16(u16* __restrict__ base,
                          const float* __restrict__ sin_t,
                          const float* __restrict__ cos_t,
                          int heads)
{
    const int idx = blockIdx.x * blockDim.x + threadIdx.x;
    const int n_elem = Tn * heads * 64;
    if (idx >= n_elem) return;
    const int i = idx & 63;
    const int h = (idx >> 6) % heads;
    const int t = idx / (64 * heads);
    const float s = sin_t[t * 64 + i];
    const float c = cos_t[t * 64 + i];
    u16* p = base + (size_t)t * LDC + h * Hn;
    const float x1 = bf_lo((unsigned int)p[i]);
    const float x2 = bf_lo((unsigned int)p[i + 64]);
    p[i]      = f2bf(x1 * c - x2 * s);
    p[i + 64] = f2bf(x2 * c + x1 * s);
}

// ---------------------------------------------------------------------------
// Flash attention, bf16 in (combined qkv, stride LDC), bf16 out (stride Dn).
// Internals fp32, identical structure to round 2.
// ---------------------------------------------------------------------------
__global__ __launch_bounds__(256) void flash_attn_bf16(
    const u16* __restrict__ qkv, u16* __restrict__ o)
{
    const int qt = (int)(gridDim.x - 1 - blockIdx.x);   // heavy tiles first
    const int n  = blockIdx.y;
    const int kh = n / Gn;
    const int tid = threadIdx.x;
    const int tx = tid & 15;
    const int ty = tid >> 4;

    __shared__ __align__(16) float Qs[Hn][BQ + 4];
    __shared__ __align__(16) float Ks[32][BS + 4];
    __shared__ __align__(16) float Sc[BQ][BS + 4];
    __shared__ __align__(16) float Vs[16][Hn + 4];
    __shared__ float mrow[BQ], lrow[BQ], arow[BQ];
    __shared__ float red[256];

    // ---- load Q tile (transposed into LDS, pre-scaled) ----
    {
        const int m  = tid >> 2;
        const int c0 = (tid & 3) * 32;
        const u16* qrow = qkv + (size_t)(qt * BQ + m) * LDC + n * Hn + c0;
        #pragma unroll
        for (int c8 = 0; c8 < 4; ++c8) {
            const uint4 u = *(const uint4*)(qrow + c8 * 8);
            Qs[c0 + c8 * 8 + 0][m] = bf_lo(u.x) * SCALE;
            Qs[c0 + c8 * 8 + 1][m] = bf_hi(u.x) * SCALE;
            Qs[c0 + c8 * 8 + 2][m] = bf_lo(u.y) * SCALE;
            Qs[c0 + c8 * 8 + 3][m] = bf_hi(u.y) * SCALE;
            Qs[c0 + c8 * 8 + 4][m] = bf_lo(u.z) * SCALE;
            Qs[c0 + c8 * 8 + 5][m] = bf_hi(u.z) * SCALE;
            Qs[c0 + c8 * 8 + 6][m] = bf_lo(u.w) * SCALE;
            Qs[c0 + c8 * 8 + 7][m] = bf_hi(u.w) * SCALE;
        }
    }
    if (tid < BQ) { mrow[tid] = -3.0e38f; lrow[tid] = 0.f; }

    float oacc[4][8] = {};

    for (int st = 0; st <= qt; ++st) {
        // ---------------- QK^T ----------------
        float sacc[4][4] = {};
        #pragma unroll 1
        for (int dc = 0; dc < 4; ++dc) {
            __syncthreads();
            {
                const int s  = tid >> 2;
                const int c0 = (tid & 3) * 8;
                const u16* krow = qkv + (size_t)(st * BS + s) * LDC + KOFF + kh * Hn + dc * 32 + c0;
                const uint4 u = *(const uint4*)krow;
                Ks[c0 + 0][s] = bf_lo(u.x); Ks[c0 + 1][s] = bf_hi(u.x);
                Ks[c0 + 2][s] = bf_lo(u.y); Ks[c0 + 3][s] = bf_hi(u.y);
                Ks[c0 + 4][s] = bf_lo(u.z); Ks[c0 + 5][s] = bf_hi(u.z);
                Ks[c0 + 6][s] = bf_lo(u.w); Ks[c0 + 7][s] = bf_hi(u.w);
            }
            __syncthreads();
            #pragma unroll
            for (int kk = 0; kk < 32; ++kk) {
                const float4 av = *(const float4*)&Qs[dc * 32 + kk][ty * 4];
                const float4 bv = *(const float4*)&Ks[kk][tx * 4];
                const float a[4] = {av.x, av.y, av.z, av.w};
                const float b[4] = {bv.x, bv.y, bv.z, bv.w};
                #pragma unroll
                for (int i = 0; i < 4; ++i)
                    #pragma unroll
                    for (int j = 0; j < 4; ++j)
                        sacc[i][j] += a[i] * b[j];
            }
        }

        if (st == qt) {
            #pragma unroll
            for (int i = 0; i < 4; ++i)
                #pragma unroll
                for (int j = 0; j < 4; ++j)
                    if (tx * 4 + j > ty * 4 + i) sacc[i][j] = -3.0e38f;
        }

        #pragma unroll
        for (int i = 0; i < 4; ++i)
            *(float4*)&Sc[ty * 4 + i][tx * 4] =
                make_float4(sacc[i][0], sacc[i][1], sacc[i][2], sacc[i][3]);
        __syncthreads();

        if (tid < BQ) {
            float rmax = -3.0e38f;
            #pragma unroll
            for (int j4 = 0; j4 < 16; ++j4) {
                const float4 s4 = *(const float4*)&Sc[tid][j4 * 4];
                rmax = fmaxf(rmax, fmaxf(fmaxf(s4.x, s4.y), fmaxf(s4.z, s4.w)));
            }
            const float mnew = fmaxf(mrow[tid], rmax);
            arow[tid] = __expf(mrow[tid] - mnew);
            mrow[tid] = mnew;
        }
        __syncthreads();

        #pragma unroll
        for (int i = 0; i < 4; ++i) {
            const float a = arow[ty * 4 + i];
            #pragma unroll
            for (int j = 0; j < 8; ++j) oacc[i][j] *= a;
        }

        {
            const int r  = tid >> 2;
            const int c0 = (tid & 3) * 16;
            const float mr = mrow[r];
            float psum = 0.f;
            #pragma unroll
            for (int c4 = 0; c4 < 4; ++c4) {
                float4 s4 = *(float4*)&Sc[r][c0 + c4 * 4];
                s4.x = __expf(s4.x - mr);
                s4.y = __expf(s4.y - mr);
                s4.z = __expf(s4.z - mr);
                s4.w = __expf(s4.w - mr);
                *(float4*)&Sc[r][c0 + c4 * 4] = s4;
                psum += s4.x + s4.y + s4.z + s4.w;
            }
            red[tid] = psum;
        }
        __syncthreads();
        if (tid < BQ)
            lrow[tid] = lrow[tid] * arow[tid] +
                        red[tid * 4] + red[tid * 4 + 1] +
                        red[tid * 4 + 2] + red[tid * 4 + 3];

        // ---------------- PV ----------------
        #pragma unroll 1
        for (int sc4 = 0; sc4 < 4; ++sc4) {
            __syncthreads();
            {
                const int s  = tid >> 4;
                const int d0 = (tid & 15) * 8;
                const u16* vrow = qkv + (size_t)(st * BS + sc4 * 16 + s) * LDC + VOFF + kh * Hn + d0;
                const uint4 u = *(const uint4*)vrow;
                Vs[s][d0 + 0] = bf_lo(u.x); Vs[s][d0 + 1] = bf_hi(u.x);
                Vs[s][d0 + 2] = bf_lo(u.y); Vs[s][d0 + 3] = bf_hi(u.y);
                Vs[s][d0 + 4] = bf_lo(u.z); Vs[s][d0 + 5] = bf_hi(u.z);
                Vs[s][d0 + 6] = bf_lo(u.w); Vs[s][d0 + 7] = bf_hi(u.w);
            }
            __syncthreads();
            #pragma unroll
            for (int ss = 0; ss < 16; ++ss) {
                const float4 v0 = *(const float4*)&Vs[ss][tx * 4];
                const float4 v1 = *(const float4*)&Vs[ss][64 + tx * 4];
                #pragma unroll
                for (int i = 0; i < 4; ++i) {
                    const float p = Sc[ty * 4 + i][sc4 * 16 + ss];
                    oacc[i][0] += p * v0.x; oacc[i][1] += p * v0.y;
                    oacc[i][2] += p * v0.z; oacc[i][3] += p * v0.w;
                    oacc[i][4] += p * v1.x; oacc[i][5] += p * v1.y;
                    oacc[i][6] += p * v1.z; oacc[i][7] += p * v1.w;
                }
            }
        }
    }
    __syncthreads();

    // epilogue: divide by l, store bf16
    #pragma unroll
    for (int i = 0; i < 4; ++i) {
        const int m = ty * 4 + i;
        const float inv = 1.0f / lrow[m];
        u16* orow = o + (size_t)(qt * BQ + m) * Dn + n * Hn;
        *(ushort4*)(orow + tx * 4) = make_ushort4(
            f2bf(oacc[i][0] * inv), f2bf(oacc[i][1] * inv),
            f2bf(oacc[i][2] * inv), f2bf(oacc[i][3] * inv));
        *(ushort4*)(orow + 64 + tx * 4) = make_ushort4(
            f2bf(oacc[i][4] * inv), f2bf(oacc[i][5] * inv),
            f2bf(oacc[i][6] * inv), f2bf(oacc[i][7] * inv));
    }
}

// ---------------------------------------------------------------------------
// Launch
// ---------------------------------------------------------------------------
extern "C" void kernel_launch(void* const* d_in, const int* in_sizes, int n_in,
                              void* d_out, int out_size, void* d_ws, size_t ws_size,
                              hipStream_t stream)
{
    const float* x      = (const float*)d_in[0];
    const float* sin_t  = (const float*)d_in[2];
    const float* cos_t  = (const float*)d_in[3];
    const float* wq     = (const float*)d_in[4];
    const float* wk     = (const float*)d_in[5];
    const float* wv     = (const float*)d_in[6];
    const float* wo     = (const float*)d_in[7];
    const float* q_bias = (const float*)d_in[8];
    const float* k_bias = (const float*)d_in[9];
    const float* v_bias = (const float*)d_in[10];
    float* out = (float*)d_out;

    // Workspace (66.6 MB total, <= proven 67.1 MB):
    char* ws = (char*)d_ws;
    u16*  cqkv = (u16*)ws;                                  // 2048*4608 bf16 = 18,874,368 B
    u16*  abuf = (u16*)(ws + 18874368);                     // 2048*3584 bf16 = 14,680,064 B
    u16*  wt   = (u16*)(ws + 18874368 + 14680064);          // 4608*3584 bf16 = 33,030,144 B (reused for woT)
    float* bqkv = (float*)(ws + 66584576);                  // 4608 fp32
    // x-bf16 scratch lives in d_out (dead before final GEMM writes it)
    u16*  xb   = (u16*)d_out;

    // 1) casts / transposes
    cast_f32_bf16<<<(Tn * Dn / 4 + 255) / 256, 256, 0, stream>>>(x, xb, Tn * Dn / 4);
    transpose_cast<<<dim3(Dn / 32, Dn / 32), 256, 0, stream>>>(wq, wt, Dn, Dn, Dn);
    transpose_cast<<<dim3(512 / 32, Dn / 32), 256, 0, stream>>>(wk, wt + (size_t)KOFF * Dn, Dn, 512, Dn);
    transpose_cast<<<dim3(512 / 32, Dn / 32), 256, 0, stream>>>(wv, wt + (size_t)VOFF * Dn, Dn, 512, Dn);
    concat_bias<<<18, 256, 0, stream>>>(q_bias, k_bias, v_bias, bqkv);

    // 2) fused QKV projection (bf16 MFMA), writes combined qkv bf16
    gemm_bf16_mfma<u16><<<dim3(LDC / GN, Tn / GM), 256, 0, stream>>>(
        xb, wt, bqkv, cqkv, Tn, LDC, Dn, LDC);

    // 3) RoPE on q and k (in place, bf16)
    rope_bf16<<<(Tn * NH * 64 + 255) / 256, 256, 0, stream>>>(cqkv, sin_t, cos_t, NH);
    rope_bf16<<<(Tn * KHn * 64 + 255) / 256, 256, 0, stream>>>(cqkv + KOFF, sin_t, cos_t, KHn);

    // 4) attention (fp32 internals, bf16 I/O)
    flash_attn_bf16<<<dim3(Tn / BQ, NH), 256, 0, stream>>>(cqkv, abuf);

    // 5) output projection: transpose wo (reuses wt), then bf16 MFMA GEMM -> fp32 out
    transpose_cast<<<dim3(Dn / 32, Dn / 32), 256, 0, stream>>>(wo, wt, Dn, Dn, Dn);
    gemm_bf16_mfma<float><<<dim3(Dn / GN, Tn / GM), 256, 0, stream>>>(
        abuf, wt, nullptr, out, Tn, Dn, Dn, Dn);
}

// Round 4
// 666.408 us; speedup vs baseline: 13.5142x; 2.1214x over previous
//
#include <hip/hip_runtime.h>
#include <hip/hip_bf16.h>
#include <math.h>

// Problem constants
#define Tn 2048
#define Dn 3584
#define NH 28
#define KHn 4
#define Hn 128
#define Gn 7            // NH / KHn
#define SCALE 0.08838834764831845f  // 1/sqrt(128)
#define LDC 4608        // combined qkv row stride (q:0..3583, k:3584..4095, v:4096..4607)
#define KOFF 3584
#define VOFF 4096
// flash tiles
#define FBQ 128
#define FBS 64

typedef unsigned short u16;
typedef __attribute__((ext_vector_type(8))) short short8;   // 8 bf16 (4 VGPRs)
typedef __attribute__((ext_vector_type(4))) float floatx4;  // MFMA acc

// ---------------- bf16 helpers ----------------
__device__ __forceinline__ float bf_lo(unsigned int u) {
    union { unsigned int i; float f; } x; x.i = u << 16; return x.f;
}
__device__ __forceinline__ u16 f2bf(float f) {
    __hip_bfloat16 h = __float2bfloat16(f);
    return *reinterpret_cast<u16*>(&h);
}

// ---------------------------------------------------------------------------
// x fp32 -> bf16 cast (vectorized)
// ---------------------------------------------------------------------------
__global__ void cast_f32_bf16(const float* __restrict__ in, u16* __restrict__ out, int n4)
{
    const int idx = blockIdx.x * blockDim.x + threadIdx.x;
    if (idx >= n4) return;
    const float4 f = ((const float4*)in)[idx];
    ((ushort4*)out)[idx] = make_ushort4(f2bf(f.x), f2bf(f.y), f2bf(f.z), f2bf(f.w));
}

// ---------------------------------------------------------------------------
// Transpose + cast: out[c][r] = bf16(in[r][c]); in (R x C) fp32, out stride ldo.
// ---------------------------------------------------------------------------
__global__ __launch_bounds__(256) void transpose_cast(
    const float* __restrict__ in, u16* __restrict__ out, int R, int C, int ldo)
{
    __shared__ float ts[32][33];
    const int tid = threadIdx.x;
    const int c0 = blockIdx.x * 32, r0 = blockIdx.y * 32;
    const int tx = tid & 31, ty = tid >> 5;  // ty 0..7
    #pragma unroll
    for (int i = 0; i < 4; ++i)
        ts[ty + i * 8][tx] = in[(size_t)(r0 + ty + i * 8) * C + c0 + tx];
    __syncthreads();
    #pragma unroll
    for (int i = 0; i < 4; ++i)
        out[(size_t)(c0 + ty + i * 8) * ldo + r0 + tx] = f2bf(ts[tx][ty + i * 8]);
}

// ---------------------------------------------------------------------------
// Transpose V out of combined qkv: vt[D][s] = qkv[s][VOFF + D], D in [0,512)
// ---------------------------------------------------------------------------
__global__ __launch_bounds__(256) void transpose_v(
    const u16* __restrict__ qkv, u16* __restrict__ vt)
{
    __shared__ u16 ts[32][33];
    const int tid = threadIdx.x;
    const int s0 = blockIdx.x * 32, d0 = blockIdx.y * 32;
    const int tx = tid & 31, ty = tid >> 5;
    #pragma unroll
    for (int i = 0; i < 4; ++i)
        ts[ty + i * 8][tx] = qkv[(size_t)(s0 + ty + i * 8) * LDC + VOFF + d0 + tx];
    __syncthreads();
    #pragma unroll
    for (int i = 0; i < 4; ++i)
        vt[(size_t)(d0 + ty + i * 8) * Tn + s0 + tx] = ts[tx][ty + i * 8];
}

// ---------------------------------------------------------------------------
// Concat bias: [q_bias | k_bias | v_bias] -> 4608
// ---------------------------------------------------------------------------
__global__ void concat_bias(const float* __restrict__ qb, const float* __restrict__ kb,
                            const float* __restrict__ vb, float* __restrict__ out)
{
    const int j = blockIdx.x * blockDim.x + threadIdx.x;
    if (j >= 4608) return;
    out[j] = j < 3584 ? qb[j] : (j < 4096 ? kb[j - 3584] : vb[j - 4096]);
}

// ---------------------------------------------------------------------------
// bf16 MFMA GEMM (m97 structure): C[M x N] = A[M x K] * Bt[N x K]^T (+bias)
// ---------------------------------------------------------------------------
#define GM 128
#define GN 128
#define GK 32

__device__ __forceinline__ void async16(const void* g, void* l) {
    __builtin_amdgcn_global_load_lds(
        (const __attribute__((address_space(1))) unsigned int*)g,
        (__attribute__((address_space(3))) unsigned int*)l, 16, 0, 0);
}

template <typename OUT_T>
__global__ __launch_bounds__(256) void gemm_bf16_mfma(
    const u16* __restrict__ A, const u16* __restrict__ Bt,
    const float* __restrict__ bias, OUT_T* __restrict__ C,
    int M, int N, int K, int ldc)
{
    __shared__ __align__(16) u16 As[GM * GK];   // 8 KB
    __shared__ __align__(16) u16 Bs[GN * GK];   // 8 KB

    const int tid  = threadIdx.x;
    const int lane = tid & 63;
    const int wave = tid >> 6;
    const int wr = wave >> 1, wc = wave & 1;
    const int m16 = lane & 15, quad = lane >> 4;

    const int bm = blockIdx.y * GM;
    const int bn = blockIdx.x * GN;

    floatx4 acc[4][4];
    #pragma unroll
    for (int i = 0; i < 4; ++i)
        #pragma unroll
        for (int j = 0; j < 4; ++j) acc[i][j] = (floatx4)0.f;

    const int rl   = lane >> 2;
    const int kcol = (lane & 3) * 8;

    for (int k0 = 0; k0 < K; k0 += GK) {
        __syncthreads();
        #pragma unroll
        for (int i = 0; i < 2; ++i) {
            const int c = wave + i * 4;
            const int row = c * 16 + rl;
            async16(A  + (size_t)(bm + row) * K + k0 + kcol, &As[c * 512]);
            async16(Bt + (size_t)(bn + row) * K + k0 + kcol, &Bs[c * 512]);
        }
        __builtin_amdgcn_s_waitcnt(0);
        __syncthreads();

        short8 af[4], bfr[4];
        #pragma unroll
        for (int i = 0; i < 4; ++i)
            af[i] = *(const short8*)&As[(wr * 64 + i * 16 + m16) * GK + quad * 8];
        #pragma unroll
        for (int j = 0; j < 4; ++j)
            bfr[j] = *(const short8*)&Bs[(wc * 64 + j * 16 + m16) * GK + quad * 8];
        #pragma unroll
        for (int i = 0; i < 4; ++i)
            #pragma unroll
            for (int j = 0; j < 4; ++j)
                acc[i][j] = __builtin_amdgcn_mfma_f32_16x16x32_bf16(
                    af[i], bfr[j], acc[i][j], 0, 0, 0);
    }

    #pragma unroll
    for (int j = 0; j < 4; ++j) {
        const int col = bn + wc * 64 + j * 16 + m16;
        const float bv = bias ? bias[col] : 0.f;
        #pragma unroll
        for (int i = 0; i < 4; ++i) {
            const int rbase = bm + wr * 64 + i * 16 + quad * 4;
            #pragma unroll
            for (int r = 0; r < 4; ++r) {
                const float v = acc[i][j][r] + bv;
                if constexpr (sizeof(OUT_T) == 2)
                    C[(size_t)(rbase + r) * ldc + col] = (OUT_T)f2bf(v);
                else
                    C[(size_t)(rbase + r) * ldc + col] = v;
            }
        }
    }
}

// ---------------------------------------------------------------------------
// RoPE in place on bf16 strided buffer
// ---------------------------------------------------------------------------
__global__ void rope_bf16(u16* __restrict__ base,
                          const float* __restrict__ sin_t,
                          const float* __restrict__ cos_t,
                          int heads)
{
    const int idx = blockIdx.x * blockDim.x + threadIdx.x;
    const int n_elem = Tn * heads * 64;
    if (idx >= n_elem) return;
    const int i = idx & 63;
    const int h = (idx >> 6) % heads;
    const int t = idx / (64 * heads);
    const float s = sin_t[t * 64 + i];
    const float c = cos_t[t * 64 + i];
    u16* p = base + (size_t)t * LDC + h * Hn;
    const float x1 = bf_lo((unsigned int)p[i]);
    const float x2 = bf_lo((unsigned int)p[i + 64]);
    p[i]      = f2bf(x1 * c - x2 * s);
    p[i + 64] = f2bf(x2 * c + x1 * s);
}

// ---------------------------------------------------------------------------
// MFMA flash attention.
// Block = 128 q-rows x head. 256 thr = 4 waves; wave owns 32 rows (2 strips).
// QK^T and PV via 16x16x32 bf16 MFMA. Online softmax wave-private (shfl).
// qkv: combined bf16 (stride LDC); vt: V^T [512][2048]; o: bf16 (stride Dn).
// ---------------------------------------------------------------------------
__global__ __launch_bounds__(256, 2) void flash_attn_mfma(
    const u16* __restrict__ qkv, const u16* __restrict__ vt, u16* __restrict__ o)
{
    const int qt = (int)(gridDim.x - 1 - blockIdx.x);   // heavy tiles first
    const int n  = blockIdx.y;
    const int kh = n / Gn;
    const int tid  = threadIdx.x;
    const int lane = tid & 63;
    const int w    = tid >> 6;
    const int m16  = lane & 15;
    const int quad = lane >> 4;

    // padded LDS: fragment ds_read_b128 at 2-way bank aliasing (free)
    __shared__ __align__(16) u16 Ks[64 * 136];    // K tile [s][d], stride 136
    __shared__ __align__(16) u16 Vs[128 * 72];    // V^T tile [d][s], stride 72
    __shared__ __align__(16) u16 Ps[128 * 72];    // P [m][s], stride 72 (wave-private rows)

    // Q fragments (A-operand), rows w*32 + p*16 + m16, loaded once
    short8 qf[2][4];
    #pragma unroll
    for (int p = 0; p < 2; ++p) {
        const int qrow = qt * FBQ + w * 32 + p * 16 + m16;
        const u16* qp = qkv + (size_t)qrow * LDC + n * Hn;
        #pragma unroll
        for (int kc = 0; kc < 4; ++kc)
            qf[p][kc] = *(const short8*)(qp + kc * 32 + quad * 8);
    }

    floatx4 oacc[2][8];
    #pragma unroll
    for (int p = 0; p < 2; ++p)
        #pragma unroll
        for (int jn = 0; jn < 8; ++jn) oacc[p][jn] = (floatx4)0.f;
    float mrow[2][4], lrow[2][4];
    #pragma unroll
    for (int p = 0; p < 2; ++p)
        #pragma unroll
        for (int r = 0; r < 4; ++r) { mrow[p][r] = -3.0e38f; lrow[p][r] = 0.f; }

    const int nst = 2 * qt + 2;
    for (int st = 0; st < nst; ++st) {
        // ---- stage K tile and V^T tile (VGPR round trip, padded strides) ----
        uint4 kv[4], vv[4];
        const int krow = tid >> 2, kseg = tid & 3;
        const int vrow = tid >> 1, vseg = tid & 1;
        {
            const u16* kp = qkv + (size_t)(st * FBS + krow) * LDC + KOFF + kh * Hn + kseg * 32;
            #pragma unroll
            for (int i = 0; i < 4; ++i) kv[i] = *(const uint4*)(kp + i * 8);
            const u16* vp = vt + (size_t)(kh * Hn + vrow) * Tn + st * FBS + vseg * 32;
            #pragma unroll
            for (int i = 0; i < 4; ++i) vv[i] = *(const uint4*)(vp + i * 8);
        }
        __syncthreads();   // previous iteration's LDS reads done
        #pragma unroll
        for (int i = 0; i < 4; ++i)
            *(uint4*)&Ks[krow * 136 + kseg * 32 + i * 8] = kv[i];
        #pragma unroll
        for (int i = 0; i < 4; ++i)
            *(uint4*)&Vs[vrow * 72 + vseg * 32 + i * 8] = vv[i];
        __syncthreads();

        // wave-uniform skip of fully-masked wave-tiles
        const bool active = (st * FBS) <= (qt * FBQ + w * 32 + 31);
        if (active) {
            // ---------------- QK^T ----------------
            floatx4 sacc[2][4];
            #pragma unroll
            for (int p = 0; p < 2; ++p)
                #pragma unroll
                for (int j = 0; j < 4; ++j) sacc[p][j] = (floatx4)0.f;
            #pragma unroll
            for (int j = 0; j < 4; ++j) {
                #pragma unroll
                for (int kc = 0; kc < 4; ++kc) {
                    const short8 bfv = *(const short8*)&Ks[(j * 16 + m16) * 136 + kc * 32 + quad * 8];
                    sacc[0][j] = __builtin_amdgcn_mfma_f32_16x16x32_bf16(qf[0][kc], bfv, sacc[0][j], 0, 0, 0);
                    sacc[1][j] = __builtin_amdgcn_mfma_f32_16x16x32_bf16(qf[1][kc], bfv, sacc[1][j], 0, 0, 0);
                }
            }

            const bool diag = (st >= 2 * qt);
            #pragma unroll
            for (int p = 0; p < 2; ++p) {
                // scale + causal mask
                #pragma unroll
                for (int j = 0; j < 4; ++j)
                    #pragma unroll
                    for (int r = 0; r < 4; ++r) {
                        float s = sacc[p][j][r] * SCALE;
                        if (diag) {
                            const int col = st * FBS + j * 16 + m16;
                            const int row = qt * FBQ + w * 32 + p * 16 + quad * 4 + r;
                            if (col > row) s = -1.0e30f;
                        }
                        sacc[p][j][r] = s;
                    }
                // online softmax per row (rows live in 16-lane quad-groups)
                #pragma unroll
                for (int r = 0; r < 4; ++r) {
                    float mx = fmaxf(fmaxf(sacc[p][0][r], sacc[p][1][r]),
                                     fmaxf(sacc[p][2][r], sacc[p][3][r]));
                    mx = fmaxf(mx, __shfl_xor(mx, 1));
                    mx = fmaxf(mx, __shfl_xor(mx, 2));
                    mx = fmaxf(mx, __shfl_xor(mx, 4));
                    mx = fmaxf(mx, __shfl_xor(mx, 8));
                    const float mnew  = fmaxf(mrow[p][r], mx);
                    const float alpha = __expf(mrow[p][r] - mnew);
                    mrow[p][r] = mnew;
                    float rs = 0.f;
                    #pragma unroll
                    for (int j = 0; j < 4; ++j) {
                        const float e = __expf(sacc[p][j][r] - mnew);
                        sacc[p][j][r] = e;
                        rs += e;
                    }
                    rs += __shfl_xor(rs, 1); rs += __shfl_xor(rs, 2);
                    rs += __shfl_xor(rs, 4); rs += __shfl_xor(rs, 8);
                    lrow[p][r] = lrow[p][r] * alpha + rs;
                    #pragma unroll
                    for (int jn = 0; jn < 8; ++jn) oacc[p][jn][r] *= alpha;
                    // write P row (wave-private rows -> no barrier)
                    const int prow = w * 32 + p * 16 + quad * 4 + r;
                    #pragma unroll
                    for (int j = 0; j < 4; ++j)
                        Ps[prow * 72 + j * 16 + m16] = f2bf(sacc[p][j][r]);
                }
            }

            // ---------------- PV ----------------
            #pragma unroll
            for (int kc2 = 0; kc2 < 2; ++kc2) {
                const short8 af0 = *(const short8*)&Ps[(w * 32 + m16) * 72 + kc2 * 32 + quad * 8];
                const short8 af1 = *(const short8*)&Ps[(w * 32 + 16 + m16) * 72 + kc2 * 32 + quad * 8];
                #pragma unroll
                for (int jn = 0; jn < 8; ++jn) {
                    const short8 bfv = *(const short8*)&Vs[(jn * 16 + m16) * 72 + kc2 * 32 + quad * 8];
                    oacc[0][jn] = __builtin_amdgcn_mfma_f32_16x16x32_bf16(af0, bfv, oacc[0][jn], 0, 0, 0);
                    oacc[1][jn] = __builtin_amdgcn_mfma_f32_16x16x32_bf16(af1, bfv, oacc[1][jn], 0, 0, 0);
                }
            }
        }
    }

    // epilogue: divide by l, store bf16
    #pragma unroll
    for (int p = 0; p < 2; ++p)
        #pragma unroll
        for (int r = 0; r < 4; ++r) {
            const float inv = 1.0f / lrow[p][r];
            const int row = qt * FBQ + w * 32 + p * 16 + quad * 4 + r;
            u16* orow = o + (size_t)row * Dn + n * Hn;
            #pragma unroll
            for (int jn = 0; jn < 8; ++jn)
                orow[jn * 16 + m16] = f2bf(oacc[p][jn][r] * inv);
        }
}

// ---------------------------------------------------------------------------
// Launch
// ---------------------------------------------------------------------------
extern "C" void kernel_launch(void* const* d_in, const int* in_sizes, int n_in,
                              void* d_out, int out_size, void* d_ws, size_t ws_size,
                              hipStream_t stream)
{
    const float* x      = (const float*)d_in[0];
    const float* sin_t  = (const float*)d_in[2];
    const float* cos_t  = (const float*)d_in[3];
    const float* wq     = (const float*)d_in[4];
    const float* wk     = (const float*)d_in[5];
    const float* wv     = (const float*)d_in[6];
    const float* wo     = (const float*)d_in[7];
    const float* q_bias = (const float*)d_in[8];
    const float* k_bias = (const float*)d_in[9];
    const float* v_bias = (const float*)d_in[10];
    float* out = (float*)d_out;

    // Workspace layout (same 66.6 MB footprint as round 3):
    char* ws = (char*)d_ws;
    u16*  cqkv = (u16*)ws;                                  // 2048*4608 bf16
    u16*  abuf = (u16*)(ws + 18874368);                     // 2048*3584 bf16
    u16*  wt   = (u16*)(ws + 18874368 + 14680064);          // 4608*3584 bf16 (reused for woT)
    float* bqkv = (float*)(ws + 66584576);                  // 4608 fp32
    u16*  vtg  = wt;        // V^T [512][2048] (2 MB) aliases wt: wqT dead after QKV GEMM
    u16*  xb   = (u16*)d_out;   // x-bf16 scratch in d_out (dead before final GEMM)

    // 1) casts / transposes / bias concat
    cast_f32_bf16<<<(Tn * Dn / 4 + 255) / 256, 256, 0, stream>>>(x, xb, Tn * Dn / 4);
    transpose_cast<<<dim3(Dn / 32, Dn / 32), 256, 0, stream>>>(wq, wt, Dn, Dn, Dn);
    transpose_cast<<<dim3(512 / 32, Dn / 32), 256, 0, stream>>>(wk, wt + (size_t)KOFF * Dn, Dn, 512, Dn);
    transpose_cast<<<dim3(512 / 32, Dn / 32), 256, 0, stream>>>(wv, wt + (size_t)VOFF * Dn, Dn, 512, Dn);
    concat_bias<<<18, 256, 0, stream>>>(q_bias, k_bias, v_bias, bqkv);

    // 2) fused QKV projection (bf16 MFMA)
    gemm_bf16_mfma<u16><<<dim3(LDC / GN, Tn / GM), 256, 0, stream>>>(
        xb, wt, bqkv, cqkv, Tn, LDC, Dn, LDC);

    // 3) RoPE on q and k
    rope_bf16<<<(Tn * NH * 64 + 255) / 256, 256, 0, stream>>>(cqkv, sin_t, cos_t, NH);
    rope_bf16<<<(Tn * KHn * 64 + 255) / 256, 256, 0, stream>>>(cqkv + KOFF, sin_t, cos_t, KHn);

    // 4) V^T extraction (overwrites dead wqT region)
    transpose_v<<<dim3(Tn / 32, 512 / 32), 256, 0, stream>>>(cqkv, vtg);

    // 5) MFMA flash attention
    flash_attn_mfma<<<dim3(Tn / FBQ, NH), 256, 0, stream>>>(cqkv, vtg, abuf);

    // 6) output projection: transpose wo (after attention: overwrites vtg), GEMM
    transpose_cast<<<dim3(Dn / 32, Dn / 32), 256, 0, stream>>>(wo, wt, Dn, Dn, Dn);
    gemm_bf16_mfma<float><<<dim3(Dn / GN, Tn / GM), 256, 0, stream>>>(
        abuf, wt, nullptr, out, Tn, Dn, Dn, Dn);
}

// Round 7
// 599.986 us; speedup vs baseline: 15.0103x; 1.1107x over previous
//
#include <hip/hip_runtime.h>
#include <hip/hip_bf16.h>
#include <math.h>

// Problem constants
#define Tn 2048
#define Dn 3584
#define NH 28
#define KHn 4
#define Hn 128
#define Gn 7            // NH / KHn
#define SCALE 0.08838834764831845f  // 1/sqrt(128)
#define LDC 4608        // combined qkv row stride (q:0..3583, k:3584..4095, v:4096..4607)
#define KOFF 3584
#define VOFF 4096
// flash tiles
#define FBQ 128
#define FBS 64

typedef unsigned short u16;
typedef __attribute__((ext_vector_type(8))) short short8;   // 8 bf16 (4 VGPRs)
typedef __attribute__((ext_vector_type(4))) float floatx4;  // MFMA acc

// ---------------- bf16 helpers ----------------
__device__ __forceinline__ float bf_lo(unsigned int u) {
    union { unsigned int i; float f; } x; x.i = u << 16; return x.f;
}
__device__ __forceinline__ u16 f2bf(float f) {
    __hip_bfloat16 h = __float2bfloat16(f);
    return *reinterpret_cast<u16*>(&h);
}

// ---------------------------------------------------------------------------
// x fp32 -> bf16 cast (vectorized)
// ---------------------------------------------------------------------------
__global__ void cast_f32_bf16(const float* __restrict__ in, u16* __restrict__ out, int n4)
{
    const int idx = blockIdx.x * blockDim.x + threadIdx.x;
    if (idx >= n4) return;
    const float4 f = ((const float4*)in)[idx];
    ((ushort4*)out)[idx] = make_ushort4(f2bf(f.x), f2bf(f.y), f2bf(f.z), f2bf(f.w));
}

// ---------------------------------------------------------------------------
// Transpose + cast: out[c][r] = bf16(in[r][c]); in (R x C) fp32, out stride ldo.
// ---------------------------------------------------------------------------
__global__ __launch_bounds__(256) void transpose_cast(
    const float* __restrict__ in, u16* __restrict__ out, int R, int C, int ldo)
{
    __shared__ float ts[32][33];
    const int tid = threadIdx.x;
    const int c0 = blockIdx.x * 32, r0 = blockIdx.y * 32;
    const int tx = tid & 31, ty = tid >> 5;  // ty 0..7
    #pragma unroll
    for (int i = 0; i < 4; ++i)
        ts[ty + i * 8][tx] = in[(size_t)(r0 + ty + i * 8) * C + c0 + tx];
    __syncthreads();
    #pragma unroll
    for (int i = 0; i < 4; ++i)
        out[(size_t)(c0 + ty + i * 8) * ldo + r0 + tx] = f2bf(ts[tx][ty + i * 8]);
}

// ---------------------------------------------------------------------------
// Transpose V out of combined qkv: vt[D][s] = qkv[s][VOFF + D], D in [0,512)
// ---------------------------------------------------------------------------
__global__ __launch_bounds__(256) void transpose_v(
    const u16* __restrict__ qkv, u16* __restrict__ vt)
{
    __shared__ u16 ts[32][33];
    const int tid = threadIdx.x;
    const int s0 = blockIdx.x * 32, d0 = blockIdx.y * 32;
    const int tx = tid & 31, ty = tid >> 5;
    #pragma unroll
    for (int i = 0; i < 4; ++i)
        ts[ty + i * 8][tx] = qkv[(size_t)(s0 + ty + i * 8) * LDC + VOFF + d0 + tx];
    __syncthreads();
    #pragma unroll
    for (int i = 0; i < 4; ++i)
        vt[(size_t)(d0 + ty + i * 8) * Tn + s0 + tx] = ts[tx][ty + i * 8];
}

// ---------------------------------------------------------------------------
// Concat bias: [q_bias | k_bias | v_bias] -> 4608
// ---------------------------------------------------------------------------
__global__ void concat_bias(const float* __restrict__ qb, const float* __restrict__ kb,
                            const float* __restrict__ vb, float* __restrict__ out)
{
    const int j = blockIdx.x * blockDim.x + threadIdx.x;
    if (j >= 4608) return;
    out[j] = j < 3584 ? qb[j] : (j < 4096 ? kb[j - 3584] : vb[j - 4096]);
}

// ---------------------------------------------------------------------------
// bf16 MFMA GEMM (m97 structure): C[M x N] = A[M x K] * Bt[N x K]^T (+bias)
// ---------------------------------------------------------------------------
#define GM 128
#define GN 128
#define GK 32

__device__ __forceinline__ void async16(const void* g, void* l) {
    __builtin_amdgcn_global_load_lds(
        (const __attribute__((address_space(1))) unsigned int*)g,
        (__attribute__((address_space(3))) unsigned int*)l, 16, 0, 0);
}

template <typename OUT_T>
__global__ __launch_bounds__(256) void gemm_bf16_mfma(
    const u16* __restrict__ A, const u16* __restrict__ Bt,
    const float* __restrict__ bias, OUT_T* __restrict__ C,
    int M, int N, int K, int ldc)
{
    __shared__ __align__(16) u16 As[GM * GK];   // 8 KB
    __shared__ __align__(16) u16 Bs[GN * GK];   // 8 KB

    const int tid  = threadIdx.x;
    const int lane = tid & 63;
    const int wave = tid >> 6;
    const int wr = wave >> 1, wc = wave & 1;
    const int m16 = lane & 15, quad = lane >> 4;

    const int bm = blockIdx.y * GM;
    const int bn = blockIdx.x * GN;

    floatx4 acc[4][4];
    #pragma unroll
    for (int i = 0; i < 4; ++i)
        #pragma unroll
        for (int j = 0; j < 4; ++j) acc[i][j] = (floatx4)0.f;

    const int rl   = lane >> 2;
    const int kcol = (lane & 3) * 8;

    for (int k0 = 0; k0 < K; k0 += GK) {
        __syncthreads();
        #pragma unroll
        for (int i = 0; i < 2; ++i) {
            const int c = wave + i * 4;
            const int row = c * 16 + rl;
            async16(A  + (size_t)(bm + row) * K + k0 + kcol, &As[c * 512]);
            async16(Bt + (size_t)(bn + row) * K + k0 + kcol, &Bs[c * 512]);
        }
        __builtin_amdgcn_s_waitcnt(0);
        __syncthreads();

        short8 af[4], bfr[4];
        #pragma unroll
        for (int i = 0; i < 4; ++i)
            af[i] = *(const short8*)&As[(wr * 64 + i * 16 + m16) * GK + quad * 8];
        #pragma unroll
        for (int j = 0; j < 4; ++j)
            bfr[j] = *(const short8*)&Bs[(wc * 64 + j * 16 + m16) * GK + quad * 8];
        #pragma unroll
        for (int i = 0; i < 4; ++i)
            #pragma unroll
            for (int j = 0; j < 4; ++j)
                acc[i][j] = __builtin_amdgcn_mfma_f32_16x16x32_bf16(
                    af[i], bfr[j], acc[i][j], 0, 0, 0);
    }

    #pragma unroll
    for (int j = 0; j < 4; ++j) {
        const int col = bn + wc * 64 + j * 16 + m16;
        const float bv = bias ? bias[col] : 0.f;
        #pragma unroll
        for (int i = 0; i < 4; ++i) {
            const int rbase = bm + wr * 64 + i * 16 + quad * 4;
            #pragma unroll
            for (int r = 0; r < 4; ++r) {
                const float v = acc[i][j][r] + bv;
                if constexpr (sizeof(OUT_T) == 2)
                    C[(size_t)(rbase + r) * ldc + col] = (OUT_T)f2bf(v);
                else
                    C[(size_t)(rbase + r) * ldc + col] = v;
            }
        }
    }
}

// ---------------------------------------------------------------------------
// RoPE in place on bf16 strided buffer. heads=32 covers q (0..27) + k (28..31).
// ---------------------------------------------------------------------------
__global__ void rope_bf16(u16* __restrict__ base,
                          const float* __restrict__ sin_t,
                          const float* __restrict__ cos_t,
                          int heads)
{
    const int idx = blockIdx.x * blockDim.x + threadIdx.x;
    const int n_elem = Tn * heads * 64;
    if (idx >= n_elem) return;
    const int i = idx & 63;
    const int h = (idx >> 6) % heads;
    const int t = idx / (64 * heads);
    const float s = sin_t[t * 64 + i];
    const float c = cos_t[t * 64 + i];
    u16* p = base + (size_t)t * LDC + h * Hn;
    const float x1 = bf_lo((unsigned int)p[i]);
    const float x2 = bf_lo((unsigned int)p[i + 64]);
    p[i]      = f2bf(x1 * c - x2 * s);
    p[i + 64] = f2bf(x2 * c + x1 * s);
}

// ---------------------------------------------------------------------------
// MFMA flash attention, online softmax with lane-partial l, K/V VGPR
// prefetch, coalesced O store via LDS staging.
// Block = 128 q-rows x head. 4 waves; wave owns 32 rows (2 strips of 16).
// ---------------------------------------------------------------------------
__global__ __launch_bounds__(256, 2) void flash_attn_mfma(
    const u16* __restrict__ qkv, const u16* __restrict__ vt, u16* __restrict__ o)
{
    const int qt = (int)(gridDim.x - 1 - blockIdx.x);   // heavy tiles first
    const int n  = blockIdx.y;
    const int kh = n / Gn;
    const int tid  = threadIdx.x;
    const int lane = tid & 63;
    const int w    = tid >> 6;
    const int m16  = lane & 15;
    const int quad = lane >> 4;

    // single shared pool; epilogue O-staging aliases Ks/Vs
    __shared__ __align__(16) u16 smem[64 * 136 + 128 * 72 + 128 * 72];  // 54272 B
    u16* Ks = smem;                    // [64 s][136]
    u16* Vs = smem + 64 * 136;         // [128 d][72]
    u16* Ps = Vs + 128 * 72;           // [128 m][72]  wave-private rows
    u16* Os = smem;                    // epilogue: [128 m][136] aliases Ks+Vs

    // Q fragments (A-operand), rows w*32 + p*16 + m16, loaded once
    short8 qf[2][4];
    #pragma unroll
    for (int p = 0; p < 2; ++p) {
        const int qrow = qt * FBQ + w * 32 + p * 16 + m16;
        const u16* qp = qkv + (size_t)qrow * LDC + n * Hn;
        #pragma unroll
        for (int kc = 0; kc < 4; ++kc)
            qf[p][kc] = *(const short8*)(qp + kc * 32 + quad * 8);
    }

    floatx4 oacc[2][8];
    #pragma unroll
    for (int p = 0; p < 2; ++p)
        #pragma unroll
        for (int jn = 0; jn < 8; ++jn) oacc[p][jn] = (floatx4)0.f;
    float mrow[2][4], lrow[2][4];
    #pragma unroll
    for (int p = 0; p < 2; ++p)
        #pragma unroll
        for (int r = 0; r < 4; ++r) { mrow[p][r] = -3.0e38f; lrow[p][r] = 0.f; }

    const int krow = tid >> 2, kseg = tid & 3;
    const int vrow = tid >> 1, vseg = tid & 1;
    const int nst = 2 * qt + 2;

    // prefetch tile 0 into VGPRs
    uint4 kv[4], vv[4];
    {
        const u16* kp = qkv + (size_t)(krow) * LDC + KOFF + kh * Hn + kseg * 32;
        #pragma unroll
        for (int i = 0; i < 4; ++i) kv[i] = *(const uint4*)(kp + i * 8);
        const u16* vp = vt + (size_t)(kh * Hn + vrow) * Tn + vseg * 32;
        #pragma unroll
        for (int i = 0; i < 4; ++i) vv[i] = *(const uint4*)(vp + i * 8);
    }

    for (int st = 0; st < nst; ++st) {
        __syncthreads();   // previous iteration's LDS reads done
        #pragma unroll
        for (int i = 0; i < 4; ++i)
            *(uint4*)&Ks[krow * 136 + kseg * 32 + i * 8] = kv[i];
        #pragma unroll
        for (int i = 0; i < 4; ++i)
            *(uint4*)&Vs[vrow * 72 + vseg * 32 + i * 8] = vv[i];
        __syncthreads();

        // prefetch next tile (clamped; hidden behind this tile's compute)
        {
            const int pst = (st + 1 < nst) ? st + 1 : nst - 1;
            const u16* kp = qkv + (size_t)(pst * FBS + krow) * LDC + KOFF + kh * Hn + kseg * 32;
            #pragma unroll
            for (int i = 0; i < 4; ++i) kv[i] = *(const uint4*)(kp + i * 8);
            const u16* vp = vt + (size_t)(kh * Hn + vrow) * Tn + pst * FBS + vseg * 32;
            #pragma unroll
            for (int i = 0; i < 4; ++i) vv[i] = *(const uint4*)(vp + i * 8);
        }

        // wave-uniform skip of fully-masked wave-tiles
        const bool active = (st * FBS) <= (qt * FBQ + w * 32 + 31);
        if (active) {
            // ---------------- QK^T ----------------
            floatx4 sacc[2][4];
            #pragma unroll
            for (int p = 0; p < 2; ++p)
                #pragma unroll
                for (int j = 0; j < 4; ++j) sacc[p][j] = (floatx4)0.f;
            #pragma unroll
            for (int j = 0; j < 4; ++j) {
                #pragma unroll
                for (int kc = 0; kc < 4; ++kc) {
                    const short8 bfv = *(const short8*)&Ks[(j * 16 + m16) * 136 + kc * 32 + quad * 8];
                    sacc[0][j] = __builtin_amdgcn_mfma_f32_16x16x32_bf16(qf[0][kc], bfv, sacc[0][j], 0, 0, 0);
                    sacc[1][j] = __builtin_amdgcn_mfma_f32_16x16x32_bf16(qf[1][kc], bfv, sacc[1][j], 0, 0, 0);
                }
            }

            // ---- online softmax (lane-partial l), P store ----
            const bool diag = (st >= 2 * qt);
            #pragma unroll
            for (int p = 0; p < 2; ++p) {
                #pragma unroll
                for (int r = 0; r < 4; ++r) {
                    const int prow = w * 32 + p * 16 + quad * 4 + r;
                    const int row  = qt * FBQ + prow;
                    float sv[4];
                    #pragma unroll
                    for (int j = 0; j < 4; ++j) {
                        float s = sacc[p][j][r] * SCALE;
                        if (diag && (st * FBS + j * 16 + m16 > row)) s = -1.0e30f;
                        sv[j] = s;
                    }
                    float mx = fmaxf(fmaxf(sv[0], sv[1]), fmaxf(sv[2], sv[3]));
                    mx = fmaxf(mx, __shfl_xor(mx, 1));
                    mx = fmaxf(mx, __shfl_xor(mx, 2));
                    mx = fmaxf(mx, __shfl_xor(mx, 4));
                    mx = fmaxf(mx, __shfl_xor(mx, 8));
                    const float mnew  = fmaxf(mrow[p][r], mx);
                    const float alpha = __expf(mrow[p][r] - mnew);
                    mrow[p][r] = mnew;
                    float ls = 0.f;
                    #pragma unroll
                    for (int j = 0; j < 4; ++j) {
                        const float e = __expf(sv[j] - mnew);
                        ls += e;
                        Ps[prow * 72 + j * 16 + m16] = f2bf(e);
                    }
                    lrow[p][r] = lrow[p][r] * alpha + ls;   // lane-partial
                    #pragma unroll
                    for (int jn = 0; jn < 8; ++jn) oacc[p][jn][r] *= alpha;
                }
            }

            // ---------------- PV ----------------
            #pragma unroll
            for (int kc2 = 0; kc2 < 2; ++kc2) {
                const short8 af0 = *(const short8*)&Ps[(w * 32 + m16) * 72 + kc2 * 32 + quad * 8];
                const short8 af1 = *(const short8*)&Ps[(w * 32 + 16 + m16) * 72 + kc2 * 32 + quad * 8];
                #pragma unroll
                for (int jn = 0; jn < 8; ++jn) {
                    const short8 bfv = *(const short8*)&Vs[(jn * 16 + m16) * 72 + kc2 * 32 + quad * 8];
                    oacc[0][jn] = __builtin_amdgcn_mfma_f32_16x16x32_bf16(af0, bfv, oacc[0][jn], 0, 0, 0);
                    oacc[1][jn] = __builtin_amdgcn_mfma_f32_16x16x32_bf16(af1, bfv, oacc[1][jn], 0, 0, 0);
                }
            }
        }
    }

    // ---- epilogue: butterfly-reduce lane-partial l, normalize, store ----
    float inv[2][4];
    #pragma unroll
    for (int p = 0; p < 2; ++p)
        #pragma unroll
        for (int r = 0; r < 4; ++r) {
            float l = lrow[p][r];
            l += __shfl_xor(l, 1); l += __shfl_xor(l, 2);
            l += __shfl_xor(l, 4); l += __shfl_xor(l, 8);
            inv[p][r] = 1.0f / l;
        }

    __syncthreads();   // all waves done with Ks/Vs before Os aliasing
    #pragma unroll
    for (int p = 0; p < 2; ++p)
        #pragma unroll
        for (int r = 0; r < 4; ++r) {
            const int mrw = w * 32 + p * 16 + quad * 4 + r;
            #pragma unroll
            for (int jn = 0; jn < 8; ++jn)
                Os[mrw * 136 + jn * 16 + m16] = f2bf(oacc[p][jn][r] * inv[p][r]);
        }
    // read back coalesced: 2 lanes per row, 64 u16 each = 8 x uint4 per lane
    {
        const int mrw  = w * 32 + (lane >> 1);
        const int half = lane & 1;
        const int grow = qt * FBQ + mrw;
        u16* orow = o + (size_t)grow * Dn + n * Hn + half * 64;
        #pragma unroll
        for (int i = 0; i < 8; ++i) {
            const uint4 d = *(const uint4*)&Os[mrw * 136 + half * 64 + i * 8];
            *(uint4*)(orow + i * 8) = d;
        }
    }
}

// ---------------------------------------------------------------------------
// Launch
// ---------------------------------------------------------------------------
extern "C" void kernel_launch(void* const* d_in, const int* in_sizes, int n_in,
                              void* d_out, int out_size, void* d_ws, size_t ws_size,
                              hipStream_t stream)
{
    const float* x      = (const float*)d_in[0];
    const float* sin_t  = (const float*)d_in[2];
    const float* cos_t  = (const float*)d_in[3];
    const float* wq     = (const float*)d_in[4];
    const float* wk     = (const float*)d_in[5];
    const float* wv     = (const float*)d_in[6];
    const float* wo     = (const float*)d_in[7];
    const float* q_bias = (const float*)d_in[8];
    const float* k_bias = (const float*)d_in[9];
    const float* v_bias = (const float*)d_in[10];
    float* out = (float*)d_out;

    char* ws = (char*)d_ws;
    u16*  cqkv = (u16*)ws;                                  // 2048*4608 bf16
    u16*  abuf = (u16*)(ws + 18874368);                     // 2048*3584 bf16
    u16*  wt   = (u16*)(ws + 18874368 + 14680064);          // 4608*3584 bf16 (reused)
    float* bqkv = (float*)(ws + 66584576);                  // 4608 fp32
    u16*  vtg  = wt;        // V^T [512][2048] aliases wt (wqT dead after QKV GEMM)
    u16*  xb   = (u16*)d_out;   // x-bf16 scratch in d_out (dead before final GEMM)

    // 1) casts / transposes / bias concat
    cast_f32_bf16<<<(Tn * Dn / 4 + 255) / 256, 256, 0, stream>>>(x, xb, Tn * Dn / 4);
    transpose_cast<<<dim3(Dn / 32, Dn / 32), 256, 0, stream>>>(wq, wt, Dn, Dn, Dn);
    transpose_cast<<<dim3(512 / 32, Dn / 32), 256, 0, stream>>>(wk, wt + (size_t)KOFF * Dn, Dn, 512, Dn);
    transpose_cast<<<dim3(512 / 32, Dn / 32), 256, 0, stream>>>(wv, wt + (size_t)VOFF * Dn, Dn, 512, Dn);
    concat_bias<<<18, 256, 0, stream>>>(q_bias, k_bias, v_bias, bqkv);

    // 2) fused QKV projection (bf16 MFMA)
    gemm_bf16_mfma<u16><<<dim3(LDC / GN, Tn / GM), 256, 0, stream>>>(
        xb, wt, bqkv, cqkv, Tn, LDC, Dn, LDC);

    // 3) RoPE on q and k in one launch (heads 0..31 of combined buffer)
    rope_bf16<<<(Tn * 32 * 64 + 255) / 256, 256, 0, stream>>>(cqkv, sin_t, cos_t, 32);

    // 4) V^T extraction (overwrites dead wqT region)
    transpose_v<<<dim3(Tn / 32, 512 / 32), 256, 0, stream>>>(cqkv, vtg);

    // 5) MFMA flash attention
    flash_attn_mfma<<<dim3(Tn / FBQ, NH), 256, 0, stream>>>(cqkv, vtg, abuf);

    // 6) output projection: transpose wo (overwrites vtg region), GEMM
    transpose_cast<<<dim3(Dn / 32, Dn / 32), 256, 0, stream>>>(wo, wt, Dn, Dn, Dn);
    gemm_bf16_mfma<float><<<dim3(Dn / GN, Tn / GM), 256, 0, stream>>>(
        abuf, wt, nullptr, out, Tn, Dn, Dn, Dn);
}